// Round 4
// baseline (385.184 us; speedup 1.0000x reference)
//
#include <hip/hip_runtime.h>
#include <hip/hip_cooperative_groups.h>

namespace cg = cooperative_groups;

#define D 64
#define SH 8            // 256 cols per bucket
#define CPB 256         // 1<<SH
#define MBLK 512        // mega-kernel grid (co-resident: 27KB LDS -> 5 blocks/CU)
#define MCH 2048        // edges per mega block (8/thread in registers)

// One cooperative kernel: histogram -> hierarchical scan -> bucket scatter ->
// per-bucket column sort (CSR). Edges live in registers across phases; the
// block-local bucket scan (lstart) lives in LDS across phases.
__global__ __launch_bounds__(256) void mega(
    const int* __restrict__ es, int* __restrict__ cmat,
    int* __restrict__ bsums, int* __restrict__ packed,
    int* __restrict__ offsets, int* __restrict__ sorted_rows,
    int N, int E, int NB) {
  cg::grid_group grid = cg::this_grid();
  __shared__ int hist[512];
  __shared__ int lstart[512];
  __shared__ int gbase[512];
  __shared__ int cursor[512];
  __shared__ int sctmp[256];
  __shared__ int staged[MCH];
  __shared__ int bidl[MCH];
  __shared__ int scnt[256];
  __shared__ int scur[256];
  int t = threadIdx.x;
  int blk = blockIdx.x;
  const int NBLK = MBLK;

  // ---- phase 1: per-block histogram of own edge chunk (edges -> registers) ----
  hist[t] = 0;
  hist[t + 256] = 0;
  __syncthreads();
  int base_e = blk * MCH;
  int c[8], r[8];
#pragma unroll
  for (int j = 0; j < 8; j++) {
    int e = base_e + t + j * 256;
    if (e < E) {
      c[j] = es[e];
      r[j] = es[E + e];
      atomicAdd(&hist[c[j] >> SH], 1);
    } else {
      c[j] = -1;
    }
  }
  __syncthreads();
  // block-local exclusive scan over 512 buckets (thread t owns 2t, 2t+1)
  int h0 = hist[2 * t], h1 = hist[2 * t + 1];
  int pair = h0 + h1;
  sctmp[t] = pair;
  __syncthreads();
  for (int off = 1; off < 256; off <<= 1) {
    int v = (t >= off) ? sctmp[t - off] : 0;
    __syncthreads();
    sctmp[t] += v;
    __syncthreads();
  }
  int excl = sctmp[t] - pair;
  lstart[2 * t] = excl;
  lstart[2 * t + 1] = excl + h0;
  for (int b = t; b < NB; b += 256) cmat[b * NBLK + blk] = hist[b];
  if (blk == 0 && t == 0) offsets[N] = E;
  grid.sync();

  // ---- phase 2a: local exclusive scan of cmat in 1024-element chunks ----
  int M = NB * NBLK;
  int nch = (M + 1023) >> 10;
  if (blk < nch) {
    int base = blk * 1024 + t * 4;
    int v0 = (base + 0 < M) ? cmat[base + 0] : 0;
    int v1 = (base + 1 < M) ? cmat[base + 1] : 0;
    int v2 = (base + 2 < M) ? cmat[base + 2] : 0;
    int v3 = (base + 3 < M) ? cmat[base + 3] : 0;
    int s = v0 + v1 + v2 + v3;
    sctmp[t] = s;
    __syncthreads();
    for (int off = 1; off < 256; off <<= 1) {
      int v = (t >= off) ? sctmp[t - off] : 0;
      __syncthreads();
      sctmp[t] += v;
      __syncthreads();
    }
    int run = sctmp[t] - s;
    if (base + 0 < M) cmat[base + 0] = run;
    run += v0;
    if (base + 1 < M) cmat[base + 1] = run;
    run += v1;
    if (base + 2 < M) cmat[base + 2] = run;
    run += v2;
    if (base + 3 < M) cmat[base + 3] = run;
    if (t == 255) bsums[blk] = sctmp[255];
  }
  grid.sync();

  // ---- phase 2b: block 0 exclusive-scans the nch chunk sums ----
  if (blk == 0) {
    int v = (t < nch) ? bsums[t] : 0;
    sctmp[t] = v;
    __syncthreads();
    for (int off = 1; off < 256; off <<= 1) {
      int u = (t >= off) ? sctmp[t - off] : 0;
      __syncthreads();
      sctmp[t] += u;
      __syncthreads();
    }
    if (t < nch) bsums[t] = sctmp[t] - v;
  }
  grid.sync();

  // ---- phase 3: scatter registers -> LDS stage -> coalesced runs to packed ----
  // global prefix at flat idx = cmat[idx] + bsums[idx>>10]  (no P3 pass needed)
  for (int b = t; b < NB; b += 256) {
    int idx = b * NBLK + blk;
    gbase[b] = cmat[idx] + bsums[idx >> 10];
  }
  cursor[t] = lstart[t];
  cursor[t + 256] = lstart[t + 256];
  __syncthreads();
#pragma unroll
  for (int j = 0; j < 8; j++) {
    if (c[j] >= 0) {
      int b = c[j] >> SH;
      int rank = atomicAdd(&cursor[b], 1);
      staged[rank] = (r[j] << SH) | (c[j] & (CPB - 1));
      bidl[rank] = b;
    }
  }
  __syncthreads();
  int nloc = min(MCH, E - base_e);
  for (int i = t; i < nloc; i += 256) {
    int b = bidl[i];
    packed[gbase[b] + (i - lstart[b])] = staged[i];
  }
  grid.sync();

  // ---- phase 4: per-bucket counting sort by exact column -> CSR ----
  if (blk < NB) {
    int b = blk;
    int i0 = b * NBLK;
    int s = cmat[i0] + bsums[i0 >> 10];
    int e;
    if (b + 1 < NB) {
      int i1 = (b + 1) * NBLK;
      e = cmat[i1] + bsums[i1 >> 10];
    } else {
      e = E;
    }
    scnt[t] = 0;
    __syncthreads();
    for (int i = s + t; i < e; i += 256) atomicAdd(&scnt[packed[i] & (CPB - 1)], 1);
    __syncthreads();
    int v = scnt[t];
    sctmp[t] = v;
    __syncthreads();
    for (int off = 1; off < 256; off <<= 1) {
      int u = (t >= off) ? sctmp[t - off] : 0;
      __syncthreads();
      sctmp[t] += u;
      __syncthreads();
    }
    int ex = sctmp[t] - v;
    scur[t] = ex;
    int gc = (b << SH) + t;
    if (gc < N) offsets[gc] = s + ex;
    __syncthreads();
    for (int i = s + t; i < e; i += 256) {
      int p = packed[i];
      int rank = atomicAdd(&scur[p & (CPB - 1)], 1);
      sorted_rows[s + rank] = p >> SH;
    }
  }
}

// one 64-lane wave per node; 4 lane-groups of 16, each group owns one edge,
// lane reads one float4 of the 64-float row; 16 edges in flight (4 accs)
__global__ __launch_bounds__(256) void node_reduce(
    const float4* __restrict__ x4, const int* __restrict__ sorted_rows,
    const int* __restrict__ offsets, float* __restrict__ out, int N) {
  int gid = blockIdx.x * 256 + threadIdx.x;
  int node = gid >> 6;
  if (node >= N) return;
  int lane = threadIdx.x & 63;
  int eg = lane >> 4;
  int d16 = lane & 15;
  int start = offsets[node];
  int cnt = offsets[node + 1] - start;
  float4 a0 = make_float4(0.f, 0.f, 0.f, 0.f);
  float4 a1 = make_float4(0.f, 0.f, 0.f, 0.f);
  float4 a2 = make_float4(0.f, 0.f, 0.f, 0.f);
  float4 a3 = make_float4(0.f, 0.f, 0.f, 0.f);
  for (int base = 0; base < cnt; base += 16) {
    int k0 = base + eg;
    int k1 = base + 4 + eg;
    int k2 = base + 8 + eg;
    int k3 = base + 12 + eg;
    int r0 = (k0 < cnt) ? sorted_rows[start + k0] : -1;
    int r1 = (k1 < cnt) ? sorted_rows[start + k1] : -1;
    int r2 = (k2 < cnt) ? sorted_rows[start + k2] : -1;
    int r3 = (k3 < cnt) ? sorted_rows[start + k3] : -1;
    if (r0 >= 0) { float4 v = x4[(size_t)r0 * 16 + d16];
      a0.x += v.x; a0.y += v.y; a0.z += v.z; a0.w += v.w; }
    if (r1 >= 0) { float4 v = x4[(size_t)r1 * 16 + d16];
      a1.x += v.x; a1.y += v.y; a1.z += v.z; a1.w += v.w; }
    if (r2 >= 0) { float4 v = x4[(size_t)r2 * 16 + d16];
      a2.x += v.x; a2.y += v.y; a2.z += v.z; a2.w += v.w; }
    if (r3 >= 0) { float4 v = x4[(size_t)r3 * 16 + d16];
      a3.x += v.x; a3.y += v.y; a3.z += v.z; a3.w += v.w; }
  }
  a0.x += a1.x + a2.x + a3.x;
  a0.y += a1.y + a2.y + a3.y;
  a0.z += a1.z + a2.z + a3.z;
  a0.w += a1.w + a2.w + a3.w;
  a0.x += __shfl_xor(a0.x, 16); a0.y += __shfl_xor(a0.y, 16);
  a0.z += __shfl_xor(a0.z, 16); a0.w += __shfl_xor(a0.w, 16);
  a0.x += __shfl_xor(a0.x, 32); a0.y += __shfl_xor(a0.y, 32);
  a0.z += __shfl_xor(a0.z, 32); a0.w += __shfl_xor(a0.w, 32);
  float4* o4 = (float4*)(out + (size_t)node * 2 * D);
  if (eg == 0) {
    float inv = 1.0f / (float)(cnt > 0 ? cnt : 1);
    a0.x *= inv; a0.y *= inv; a0.z *= inv; a0.w *= inv;
    o4[d16] = a0;
  } else if (eg == 1) {
    float4 v = (cnt > 0) ? x4[(size_t)node * 16 + d16]
                         : make_float4(0.f, 0.f, 0.f, 0.f);
    o4[16 + d16] = v;
  }
}

// ---------- fallback atomic path (only if fast path inapplicable) ----------

__global__ __launch_bounds__(256) void edge_scatter_atomic(
    const int* __restrict__ es, const float* __restrict__ x,
    float* __restrict__ out, int* __restrict__ count, int E) {
  int gid = blockIdx.x * blockDim.x + threadIdx.x;
  int e = gid >> 6;
  int lane = gid & 63;
  if (e >= E) return;
  int c = es[e];
  int r = es[E + e];
  if (lane == 0) atomicAdd(&count[c], 1);
  float v = x[(size_t)r * D + lane];
  unsafeAtomicAdd(&out[(size_t)c * 2 * D + lane], v);
}

__global__ __launch_bounds__(256) void finalize_atomic(
    const float* __restrict__ x, float* __restrict__ out,
    const int* __restrict__ count, int N) {
  int gid = blockIdx.x * blockDim.x + threadIdx.x;
  int node = gid >> 5;
  int j4 = gid & 31;
  if (node >= N) return;
  int cnt = count[node];
  float4* out4 = (float4*)(out + (size_t)node * 2 * D);
  if (j4 < 16) {
    float4 s = out4[j4];
    float inv = 1.0f / (float)(cnt > 0 ? cnt : 1);
    s.x *= inv; s.y *= inv; s.z *= inv; s.w *= inv;
    out4[j4] = s;
  } else {
    float4 v;
    if (cnt > 0) {
      const float4* x4 = (const float4*)(x + (size_t)node * D);
      v = x4[j4 - 16];
    } else {
      v = make_float4(0.f, 0.f, 0.f, 0.f);
    }
    out4[j4] = v;
  }
}

extern "C" void kernel_launch(void* const* d_in, const int* in_sizes, int n_in,
                              void* d_out, int out_size, void* d_ws, size_t ws_size,
                              hipStream_t stream) {
  const float* x = (const float*)d_in[0];
  const int* es = (const int*)d_in[1];
  int N = in_sizes[0] / D;
  int E = in_sizes[1] / 2;
  float* out = (float*)d_out;

  int NB = (N + CPB - 1) >> SH;
  int M = NB * MBLK;
  size_t need = ((size_t)M + 256 + (size_t)N + 1 + 2 * (size_t)E) * sizeof(int);
  bool fast = (NB <= 512) && (E <= MBLK * MCH) && (ws_size >= need);
  if (!fast) {
    int* count = (int*)d_ws;
    hipMemsetAsync(count, 0, (size_t)N * sizeof(int), stream);
    hipMemsetAsync(out, 0, (size_t)N * 2 * D * sizeof(float), stream);
    long long t1 = (long long)E * 64;
    edge_scatter_atomic<<<(int)((t1 + 255) / 256), 256, 0, stream>>>(es, x, out, count, E);
    long long t2 = (long long)N * 32;
    finalize_atomic<<<(int)((t2 + 255) / 256), 256, 0, stream>>>(x, out, count, N);
    return;
  }

  int* ws = (int*)d_ws;
  int* cmat = ws;                        // M
  int* bsums = cmat + M;                 // 256
  int* offsets = bsums + 256;            // N+1
  int* packed = offsets + N + 1;         // E
  int* sorted_rows = packed + E;         // E

  void* args[] = {(void*)&es, (void*)&cmat, (void*)&bsums, (void*)&packed,
                  (void*)&offsets, (void*)&sorted_rows,
                  (void*)&N, (void*)&E, (void*)&NB};
  hipLaunchCooperativeKernel((const void*)mega, dim3(MBLK), dim3(256), args, 0, stream);

  long long rt = (long long)N * 64;
  node_reduce<<<(int)((rt + 255) / 256), 256, 0, stream>>>(
      (const float4*)x, sorted_rows, offsets, out, N);
}

// Round 5
// 163.408 us; speedup vs baseline: 2.3572x; 2.3572x over previous
//
#include <hip/hip_runtime.h>

#define D 64
#define SH 8            // 256 cols per bucket
#define CPB 256         // 1<<SH
#define CH 4096         // edges per block in bucket kernels
#define MAXNB 512       // fast path supports N <= 131072

// K1: per-block LDS histogram -> global bucket totals (atomic, ~391 adds/block
// on hot L2-resident counters). Last-finisher block (done-counter handshake,
// no dispatch-order assumption) scans totals -> bbase + cursor init.
__global__ __launch_bounds__(256) void count_scan(
    const int* __restrict__ es, int* __restrict__ btot,
    int* __restrict__ done, int* __restrict__ bbase,
    int* __restrict__ cursor, int* __restrict__ offsets,
    int NB, int E, int N) {
  __shared__ int hist[MAXNB];
  __shared__ int sctmp[256];
  __shared__ int lastflag;
  int t = threadIdx.x;
  hist[t] = 0;
  hist[t + 256] = 0;
  __syncthreads();
  int base_e = blockIdx.x * CH;
#pragma unroll
  for (int j = 0; j < 16; j++) {
    int e = base_e + t + j * 256;
    if (e < E) atomicAdd(&hist[es[e] >> SH], 1);
  }
  __syncthreads();
  for (int b = t; b < NB; b += 256) {
    int h = hist[b];
    if (h) atomicAdd(&btot[b], h);
  }
  // __syncthreads waits vmcnt(0) -> this block's atomics are complete at the
  // coherent point before t0 signals done.
  __syncthreads();
  if (t == 0) {
    __threadfence();
    int d = atomicAdd(done, 1);
    lastflag = (d == (int)gridDim.x - 1);
  }
  __syncthreads();
  if (!lastflag) return;
  __threadfence();
  // last block: scan NB (<=512) totals; thread t owns buckets 2t, 2t+1
  int i0 = 2 * t, i1 = 2 * t + 1;
  int h0 = (i0 < NB) ? __hip_atomic_load(&btot[i0], __ATOMIC_RELAXED,
                                         __HIP_MEMORY_SCOPE_AGENT) : 0;
  int h1 = (i1 < NB) ? __hip_atomic_load(&btot[i1], __ATOMIC_RELAXED,
                                         __HIP_MEMORY_SCOPE_AGENT) : 0;
  int pair = h0 + h1;
  sctmp[t] = pair;
  __syncthreads();
  for (int off = 1; off < 256; off <<= 1) {
    int v = (t >= off) ? sctmp[t - off] : 0;
    __syncthreads();
    sctmp[t] += v;
    __syncthreads();
  }
  int excl = sctmp[t] - pair;
  if (i0 < NB) { bbase[i0] = excl; cursor[i0] = excl; }
  if (i1 < NB) { bbase[i1] = excl + h0; cursor[i1] = excl + h0; }
  if (t == 0) { bbase[NB] = E; offsets[N] = E; }
}

// K2: re-histogram own chunk, reserve global space per bucket via one
// atomicAdd per (block,bucket), stage by local rank in LDS, write coalesced
// runs to packed. Within-bucket order across blocks is nondeterministic
// (harmless: sort_cols regroups by exact column; fp32 reorder ~1e-6).
__global__ __launch_bounds__(256) void scatter_res(
    const int* __restrict__ es, int* __restrict__ cursor,
    int* __restrict__ packed, int NB, int E) {
  __shared__ int hist[MAXNB];
  __shared__ int lstart[MAXNB];
  __shared__ int gbase[MAXNB];
  __shared__ int lcur[MAXNB];
  __shared__ int sctmp[256];
  __shared__ int staged[CH];
  __shared__ unsigned short bidl[CH];
  int t = threadIdx.x;
  hist[t] = 0;
  hist[t + 256] = 0;
  __syncthreads();
  int base_e = blockIdx.x * CH;
  int c[16], r[16];
#pragma unroll
  for (int j = 0; j < 16; j++) {
    int e = base_e + t + j * 256;
    if (e < E) {
      c[j] = es[e];
      r[j] = es[E + e];
      atomicAdd(&hist[c[j] >> SH], 1);
    } else {
      c[j] = -1;
    }
  }
  __syncthreads();
  // block-local exclusive scan over buckets (thread t owns 2t, 2t+1)
  int h0 = hist[2 * t], h1 = hist[2 * t + 1];
  int pair = h0 + h1;
  sctmp[t] = pair;
  __syncthreads();
  for (int off = 1; off < 256; off <<= 1) {
    int v = (t >= off) ? sctmp[t - off] : 0;
    __syncthreads();
    sctmp[t] += v;
    __syncthreads();
  }
  int excl = sctmp[t] - pair;
  lstart[2 * t] = excl;
  lstart[2 * t + 1] = excl + h0;
  lcur[2 * t] = excl;
  lcur[2 * t + 1] = excl + h0;
  // reserve global destination range per non-empty bucket
  for (int b = t; b < NB; b += 256) {
    int h = hist[b];
    gbase[b] = h ? atomicAdd(&cursor[b], h) : 0;
  }
  __syncthreads();
#pragma unroll
  for (int j = 0; j < 16; j++) {
    if (c[j] >= 0) {
      int b = c[j] >> SH;
      int rank = atomicAdd(&lcur[b], 1);
      staged[rank] = (r[j] << SH) | (c[j] & (CPB - 1));
      bidl[rank] = (unsigned short)b;
    }
  }
  __syncthreads();
  int nloc = min(CH, E - base_e);
  for (int i = t; i < nloc; i += 256) {
    int b = bidl[i];
    packed[gbase[b] + (i - lstart[b])] = staged[i];
  }
}

// K3: one block per bucket: counting-sort run by exact column -> CSR
__global__ __launch_bounds__(256) void sort_cols(
    const int* __restrict__ packed, const int* __restrict__ bbase,
    int* __restrict__ offsets, int* __restrict__ sorted_rows, int N) {
  __shared__ int cnt[CPB];
  __shared__ int sctmp[256];
  __shared__ int cur[CPB];
  int b = blockIdx.x;
  int t = threadIdx.x;
  int s = bbase[b], e = bbase[b + 1];
  cnt[t] = 0;
  __syncthreads();
  for (int i = s + t; i < e; i += 256) atomicAdd(&cnt[packed[i] & (CPB - 1)], 1);
  __syncthreads();
  int v = cnt[t];
  sctmp[t] = v;
  __syncthreads();
  for (int off = 1; off < 256; off <<= 1) {
    int u = (t >= off) ? sctmp[t - off] : 0;
    __syncthreads();
    sctmp[t] += u;
    __syncthreads();
  }
  int excl = sctmp[t] - v;
  cur[t] = excl;
  int gc = (b << SH) + t;
  if (gc < N) offsets[gc] = s + excl;
  __syncthreads();
  for (int i = s + t; i < e; i += 256) {
    int p = packed[i];
    int rank = atomicAdd(&cur[p & (CPB - 1)], 1);
    sorted_rows[s + rank] = p >> SH;
  }
}

// one 64-lane wave per node; 4 lane-groups of 16, each group owns one edge,
// lane reads one float4 of the 64-float row; 16 edges in flight (4 accs)
__global__ __launch_bounds__(256) void node_reduce(
    const float4* __restrict__ x4, const int* __restrict__ sorted_rows,
    const int* __restrict__ offsets, float* __restrict__ out, int N) {
  int gid = blockIdx.x * 256 + threadIdx.x;
  int node = gid >> 6;
  if (node >= N) return;
  int lane = threadIdx.x & 63;
  int eg = lane >> 4;
  int d16 = lane & 15;
  int start = offsets[node];
  int cnt = offsets[node + 1] - start;
  float4 a0 = make_float4(0.f, 0.f, 0.f, 0.f);
  float4 a1 = make_float4(0.f, 0.f, 0.f, 0.f);
  float4 a2 = make_float4(0.f, 0.f, 0.f, 0.f);
  float4 a3 = make_float4(0.f, 0.f, 0.f, 0.f);
  for (int base = 0; base < cnt; base += 16) {
    int k0 = base + eg;
    int k1 = base + 4 + eg;
    int k2 = base + 8 + eg;
    int k3 = base + 12 + eg;
    int r0 = (k0 < cnt) ? sorted_rows[start + k0] : -1;
    int r1 = (k1 < cnt) ? sorted_rows[start + k1] : -1;
    int r2 = (k2 < cnt) ? sorted_rows[start + k2] : -1;
    int r3 = (k3 < cnt) ? sorted_rows[start + k3] : -1;
    if (r0 >= 0) { float4 v = x4[(size_t)r0 * 16 + d16];
      a0.x += v.x; a0.y += v.y; a0.z += v.z; a0.w += v.w; }
    if (r1 >= 0) { float4 v = x4[(size_t)r1 * 16 + d16];
      a1.x += v.x; a1.y += v.y; a1.z += v.z; a1.w += v.w; }
    if (r2 >= 0) { float4 v = x4[(size_t)r2 * 16 + d16];
      a2.x += v.x; a2.y += v.y; a2.z += v.z; a2.w += v.w; }
    if (r3 >= 0) { float4 v = x4[(size_t)r3 * 16 + d16];
      a3.x += v.x; a3.y += v.y; a3.z += v.z; a3.w += v.w; }
  }
  a0.x += a1.x + a2.x + a3.x;
  a0.y += a1.y + a2.y + a3.y;
  a0.z += a1.z + a2.z + a3.z;
  a0.w += a1.w + a2.w + a3.w;
  a0.x += __shfl_xor(a0.x, 16); a0.y += __shfl_xor(a0.y, 16);
  a0.z += __shfl_xor(a0.z, 16); a0.w += __shfl_xor(a0.w, 16);
  a0.x += __shfl_xor(a0.x, 32); a0.y += __shfl_xor(a0.y, 32);
  a0.z += __shfl_xor(a0.z, 32); a0.w += __shfl_xor(a0.w, 32);
  float4* o4 = (float4*)(out + (size_t)node * 2 * D);
  if (eg == 0) {
    float inv = 1.0f / (float)(cnt > 0 ? cnt : 1);
    a0.x *= inv; a0.y *= inv; a0.z *= inv; a0.w *= inv;
    o4[d16] = a0;
  } else if (eg == 1) {
    float4 v = (cnt > 0) ? x4[(size_t)node * 16 + d16]
                         : make_float4(0.f, 0.f, 0.f, 0.f);
    o4[16 + d16] = v;
  }
}

// ---------- fallback atomic path (only if fast path inapplicable) ----------

__global__ __launch_bounds__(256) void edge_scatter_atomic(
    const int* __restrict__ es, const float* __restrict__ x,
    float* __restrict__ out, int* __restrict__ count, int E) {
  int gid = blockIdx.x * blockDim.x + threadIdx.x;
  int e = gid >> 6;
  int lane = gid & 63;
  if (e >= E) return;
  int c = es[e];
  int r = es[E + e];
  if (lane == 0) atomicAdd(&count[c], 1);
  float v = x[(size_t)r * D + lane];
  unsafeAtomicAdd(&out[(size_t)c * 2 * D + lane], v);
}

__global__ __launch_bounds__(256) void finalize_atomic(
    const float* __restrict__ x, float* __restrict__ out,
    const int* __restrict__ count, int N) {
  int gid = blockIdx.x * blockDim.x + threadIdx.x;
  int node = gid >> 5;
  int j4 = gid & 31;
  if (node >= N) return;
  int cnt = count[node];
  float4* out4 = (float4*)(out + (size_t)node * 2 * D);
  if (j4 < 16) {
    float4 s = out4[j4];
    float inv = 1.0f / (float)(cnt > 0 ? cnt : 1);
    s.x *= inv; s.y *= inv; s.z *= inv; s.w *= inv;
    out4[j4] = s;
  } else {
    float4 v;
    if (cnt > 0) {
      const float4* x4 = (const float4*)(x + (size_t)node * D);
      v = x4[j4 - 16];
    } else {
      v = make_float4(0.f, 0.f, 0.f, 0.f);
    }
    out4[j4] = v;
  }
}

extern "C" void kernel_launch(void* const* d_in, const int* in_sizes, int n_in,
                              void* d_out, int out_size, void* d_ws, size_t ws_size,
                              hipStream_t stream) {
  const float* x = (const float*)d_in[0];
  const int* es = (const int*)d_in[1];
  int N = in_sizes[0] / D;
  int E = in_sizes[1] / 2;
  float* out = (float*)d_out;

  int NB = (N + CPB - 1) >> SH;
  int NBLK = (E + CH - 1) / CH;
  size_t need = ((size_t)NB + 1 + (NB + 1) + NB + ((size_t)N + 1) +
                 2 * (size_t)E) * sizeof(int);
  if (NB > MAXNB || ws_size < need) {
    int* count = (int*)d_ws;
    hipMemsetAsync(count, 0, (size_t)N * sizeof(int), stream);
    hipMemsetAsync(out, 0, (size_t)N * 2 * D * sizeof(float), stream);
    long long t1 = (long long)E * 64;
    edge_scatter_atomic<<<(int)((t1 + 255) / 256), 256, 0, stream>>>(es, x, out, count, E);
    long long t2 = (long long)N * 32;
    finalize_atomic<<<(int)((t2 + 255) / 256), 256, 0, stream>>>(x, out, count, N);
    return;
  }

  int* ws = (int*)d_ws;
  int* btot = ws;                    // NB
  int* done = btot + NB;             // 1
  int* bbase = done + 1;             // NB+1
  int* cursor = bbase + NB + 1;      // NB
  int* offsets = cursor + NB;        // N+1
  int* packed = offsets + N + 1;     // E
  int* sorted_rows = packed + E;     // E

  // zero btot + done (contiguous NB+1 ints)
  hipMemsetAsync(btot, 0, ((size_t)NB + 1) * sizeof(int), stream);

  count_scan<<<NBLK, 256, 0, stream>>>(es, btot, done, bbase, cursor, offsets,
                                       NB, E, N);
  scatter_res<<<NBLK, 256, 0, stream>>>(es, cursor, packed, NB, E);
  sort_cols<<<NB, 256, 0, stream>>>(packed, bbase, offsets, sorted_rows, N);

  long long rt = (long long)N * 64;
  node_reduce<<<(int)((rt + 255) / 256), 256, 0, stream>>>(
      (const float4*)x, sorted_rows, offsets, out, N);
}